// Round 14
// baseline (74.859 us; speedup 1.0000x reference)
//
#include <hip/hip_runtime.h>
#include <stdint.h>

typedef __bf16 bf16x8 __attribute__((ext_vector_type(8)));
typedef float f32x4 __attribute__((ext_vector_type(4)));
typedef unsigned short u16;
typedef const __attribute__((address_space(1))) void* as1_cvp;
typedef __attribute__((address_space(3))) void* as3_vp;

__device__ __forceinline__ u16 f2bf(float f) {
  union { float f; unsigned u; } v; v.f = f;
  unsigned r = v.u + 0x7fffu + ((v.u >> 16) & 1u);
  return (u16)(r >> 16);
}

// ---- single-block: histogram + stable counting-sort perm + tile maps ----
__global__ __launch_bounds__(256) void hist_perm_kernel(
    const int* __restrict__ idx, int n, int* __restrict__ starts,
    int* __restrict__ perm, int* __restrict__ tmap128,
    int* __restrict__ tmap64) {
  __shared__ int cnt[4][256];
  __shared__ int gtot[4], gstart[4];
  const int t = threadIdx.x;
  const int rpt = (n + 255) >> 8;
  const int base = t * rpt;
  int c[4] = {0, 0, 0, 0};
  for (int j = 0; j < rpt; ++j) {
    const int i = base + j;
    if (i < n) c[idx[i] & 3]++;
  }
  #pragma unroll
  for (int g = 0; g < 4; ++g) cnt[g][t] = c[g];
  __syncthreads();
  const int w = t >> 6, l = t & 63;
  {
    const int s0 = cnt[w][l * 4 + 0], s1 = cnt[w][l * 4 + 1];
    const int s2 = cnt[w][l * 4 + 2], s3 = cnt[w][l * 4 + 3];
    const int sum = s0 + s1 + s2 + s3;
    int sc = sum;
    #pragma unroll
    for (int d = 1; d < 64; d <<= 1) {
      const int o = __shfl_up(sc, d, 64);
      if (l >= d) sc += o;
    }
    const int ex = sc - sum;
    cnt[w][l * 4 + 0] = ex;
    cnt[w][l * 4 + 1] = ex + s0;
    cnt[w][l * 4 + 2] = ex + s0 + s1;
    cnt[w][l * 4 + 3] = ex + s0 + s1 + s2;
    if (l == 63) gtot[w] = sc;
  }
  __syncthreads();
  if (t == 0) {
    int s = 0, nt128 = 0, nt64 = 0;
    for (int g = 0; g < 4; ++g) {
      gstart[g] = s;
      starts[g] = s;
      const int cg = gtot[g];
      for (int j = 0; j < cg; j += 128) tmap128[nt128++] = (g << 28) | (s + j);
      for (int j = 0; j < cg; j += 64)  tmap64[nt64++]  = (g << 28) | (s + j);
      s += cg;
    }
    starts[4] = s;
    while (nt128 < 20) tmap128[nt128++] = -1;
    while (nt64 < 40)  tmap64[nt64++]  = -1;
  }
  __syncthreads();
  int run[4] = {0, 0, 0, 0};
  for (int j = 0; j < rpt; ++j) {
    const int i = base + j;
    if (i < n) {
      const int g = idx[i] & 3;
      perm[gstart[g] + cnt[g][t] + run[g]] = i;
      run[g]++;
    }
  }
}

// ---- shared transpose body: W [K][N] f32 tile -> WT [N][K] bf16 ----
__device__ __forceinline__ void wtrans_body(
    float (*tile)[65], const float* __restrict__ W, u16* __restrict__ WT,
    int K, int N, int tx, int ty, int o) {
  const float* Wo = W + (size_t)o * K * N;
  u16* WTo = WT + (size_t)o * N * K;
  const int k0 = ty * 64, n0 = tx * 64;
  const int rr = threadIdx.x >> 4, cc = threadIdx.x & 15;
  #pragma unroll
  for (int j = 0; j < 4; ++j) {
    const int r = j * 16 + rr;
    const float4 v = *(const float4*)(Wo + (size_t)(k0 + r) * N + n0 + cc * 4);
    tile[r][cc * 4 + 0] = v.x; tile[r][cc * 4 + 1] = v.y;
    tile[r][cc * 4 + 2] = v.z; tile[r][cc * 4 + 3] = v.w;
  }
  __syncthreads();
  #pragma unroll
  for (int j = 0; j < 4; ++j) {
    const int nrow = j * 16 + rr;
    ushort4 u;
    u.x = f2bf(tile[cc * 4 + 0][nrow]);
    u.y = f2bf(tile[cc * 4 + 1][nrow]);
    u.z = f2bf(tile[cc * 4 + 2][nrow]);
    u.w = f2bf(tile[cc * 4 + 3][nrow]);
    *(ushort4*)(WTo + (size_t)(n0 + nrow) * K + k0 + cc * 4) = u;
  }
}

// ---- k1: W1T transpose (blocks 0..2047) ∥ x gather/convert (2048..4095) ----
__global__ __launch_bounds__(256) void w1t_gather_kernel(
    const float* __restrict__ W1, u16* __restrict__ W1T,
    const float* __restrict__ x, const int* __restrict__ perm,
    u16* __restrict__ Xs) {
  __shared__ float tile[64][65];
  const int bid = blockIdx.x;
  if (bid >= 2048) {
    const int p = bid - 2048;
    const int b = perm[p];
    const float4 v = ((const float4*)(x + (size_t)b * 1024))[threadIdx.x];
    ushort4 u;
    u.x = f2bf(v.x); u.y = f2bf(v.y); u.z = f2bf(v.z); u.w = f2bf(v.w);
    ((ushort4*)(Xs + (size_t)p * 1024))[threadIdx.x] = u;
    return;
  }
  const int xcd = bid & 7, i = bid >> 3;
  const int tx = (xcd << 2) | (i & 3);
  const int ty = (i >> 2) & 15;
  const int o = i >> 6;
  wtrans_body(tile, W1, W1T, 1024, 2048, tx, ty, o);
}

// ---- GEMM1 body: BK=32, 4 LDS buffers, 3-deep prefetch, 1 barrier/step ----
// Tile 128x128, 4 waves (2x2), wave 64x64 (4x4 frags), 16 MFMA/step/wave.
// buf = A 8KB + B 8KB = 16KB; 4 bufs = 64KB. T2 XOR (4x16B units, ^row&3).
__device__ __forceinline__ void gemm1_body(
    char* smem, int bid,
    const u16* __restrict__ A, const u16* __restrict__ BT,
    const float* __restrict__ bias, const int* __restrict__ starts,
    const int* __restrict__ tmap, u16* __restrict__ outH) {
  constexpr int NT_PAD = 20, NTN = 16, KT = 1024, NN = 2048;
  constexpr int BSTR = 16384;  // per-buffer stride (A 8KB @0, B 8KB @8192)

  const int nwg = NT_PAD * NTN;  // 320, %8==0
  const int q = nwg >> 3;
  const int swz = (bid & 7) * q + (bid >> 3);
  const int tile = swz % NT_PAD;
  const int n_t = swz / NT_PAD;

  const int tm = tmap[tile];
  if (tm < 0) return;
  const int o = tm >> 28;
  const int m_start = tm & 0x0FFFFFFF;
  const int g1 = starts[o + 1];
  const int n_start = n_t * 128;
  const u16* Bo = BT + (size_t)o * NN * KT;

  const int tid = threadIdx.x;
  const int w = tid >> 6;
  const int l = tid & 63;
  const int wm = w >> 1, wn = w & 1;

  // staging: 8KB tile = 8 chunks of 1KB (16 rows each); wave w owns 2 chunks.
  // chunk c, lane l -> row c*16 + (l>>2), unit l&3 (16B units, 4 per 64B row).
  // T2: LDS[row][u] = global[row][u ^ (row&3)] -> src unit = (l&3)^((l>>2)&3)
  const int su = ((l & 3) ^ ((l >> 2) & 3)) << 3;  // elem offset (x8 bf16)
  const u16* pA[2];
  #pragma unroll
  for (int j = 0; j < 2; ++j) {
    int r = m_start + (w * 2 + j) * 16 + (l >> 2);
    if (r >= g1) r = g1 - 1;
    pA[j] = A + (size_t)r * KT + su;
  }
  const u16* pB[2];
  #pragma unroll
  for (int j = 0; j < 2; ++j) {
    const int nr = n_start + (w * 2 + j) * 16 + (l >> 2);
    pB[j] = Bo + (size_t)nr * KT + su;
  }

#define STAGE32(dst_off)                                                       \
  {                                                                            \
    _Pragma("unroll")                                                          \
    for (int j = 0; j < 2; ++j)                                                \
      __builtin_amdgcn_global_load_lds((as1_cvp)pA[j],                         \
          (as3_vp)(smem + (dst_off) + (w * 2 + j) * 1024), 16, 0, 0);          \
    _Pragma("unroll")                                                          \
    for (int j = 0; j < 2; ++j)                                                \
      __builtin_amdgcn_global_load_lds((as1_cvp)pB[j],                         \
          (as3_vp)(smem + (dst_off) + 8192 + (w * 2 + j) * 1024), 16, 0, 0);   \
    _Pragma("unroll") for (int j = 0; j < 2; ++j) pA[j] += 32;                 \
    _Pragma("unroll") for (int j = 0; j < 2; ++j) pB[j] += 32;                 \
  }

  // read offsets: row = base + (l&15) (bases x16 -> row&3 == l&3),
  // k-group l>>4 in 0..3; T2 read XOR: unit = (l>>4) ^ (l&3).
  const int ru = ((l >> 4) ^ (l & 3)) << 4;
  const int lrow = l & 15;
  int offA[4], offB[4];
  #pragma unroll
  for (int a = 0; a < 4; ++a)
    offA[a] = (wm * 64 + a * 16 + lrow) * 64 + ru;
  #pragma unroll
  for (int b = 0; b < 4; ++b)
    offB[b] = (wn * 64 + b * 16 + lrow) * 64 + ru + 8192;

  f32x4 acc[4][4] = {};

  const int nK = KT >> 5;  // 32 steps
  STAGE32(0); STAGE32(BSTR); STAGE32(2 * BSTR);  // prologue: tiles 0,1,2
  for (int t = 0; t < nK; ++t) {
    const int cur = (t & 3) * BSTR;
    // wait for tile t: newer tiles in flight = min(2, nK-1-t) x 4 loads/wave
    if (t + 2 < nK)      asm volatile("s_waitcnt vmcnt(8)" ::: "memory");
    else if (t + 1 < nK) asm volatile("s_waitcnt vmcnt(4)" ::: "memory");
    else                 asm volatile("s_waitcnt vmcnt(0)" ::: "memory");
    __builtin_amdgcn_s_barrier();  // buf[t&3] valid; all prior reads drained

    bf16x8 af[4], bfr[4];
    #pragma unroll
    for (int a = 0; a < 4; ++a)
      af[a] = *(const bf16x8*)(smem + cur + offA[a]);
    #pragma unroll
    for (int b = 0; b < 4; ++b)
      bfr[b] = *(const bf16x8*)(smem + cur + offB[b]);
    if (t + 3 < nK) STAGE32(((t + 3) & 3) * BSTR);  // overwrite freed buffer
    asm volatile("s_waitcnt lgkmcnt(0)" ::: "memory");

    __builtin_amdgcn_s_setprio(1);
    #pragma unroll
    for (int a = 0; a < 4; ++a)
      #pragma unroll
      for (int b = 0; b < 4; ++b)
        acc[a][b] = __builtin_amdgcn_mfma_f32_16x16x32_bf16(af[a], bfr[b], acc[a][b], 0, 0, 0);
    __builtin_amdgcn_s_setprio(0);
  }
#undef STAGE32

  // epilogue: C/D layout col = l&15, row = (l>>4)*4 + r  [m89-verified]
  const int col_l = l & 15;
  const int row_l = (l >> 4) << 2;
  #pragma unroll
  for (int a = 0; a < 4; ++a) {
    #pragma unroll
    for (int b = 0; b < 4; ++b) {
      const int n = n_start + wn * 64 + b * 16 + col_l;
      const float bv = bias[n];
      #pragma unroll
      for (int r = 0; r < 4; ++r) {
        const int p = m_start + wm * 64 + a * 16 + row_l + r;
        if (p < g1) outH[(size_t)p * NN + n] = f2bf(acc[a][b][r] + bv);
      }
    }
  }
}

// ---- GEMM2 body (unchanged R12 structure): TM=64, BK=64, 2-buf, 2 barriers ----
__device__ __forceinline__ void gemm2_body(
    char* smem, int bid,
    const u16* __restrict__ A, const u16* __restrict__ BT,
    const float* __restrict__ bias, const int* __restrict__ starts,
    const int* __restrict__ tmap, const int* __restrict__ perm,
    float* __restrict__ outF) {
  constexpr int TM = 64, NT_PAD = 40, KT = 2048, NN = 1024, NTN = 8;
  constexpr int MR = TM / 32;
  constexpr int ABUF = TM * 128;
  constexpr int BSTR = ABUF + 16384;

  const int nwg = NT_PAD * NTN;
  const int q = nwg >> 3;
  const int swz = (bid & 7) * q + (bid >> 3);
  const int tile = swz % NT_PAD;
  const int n_t = swz / NT_PAD;

  const int tm = tmap[tile];
  if (tm < 0) return;
  const int o = tm >> 28;
  const int m_start = tm & 0x0FFFFFFF;
  const int g1 = starts[o + 1];
  const int n_start = n_t * 128;
  const u16* Bo = BT + (size_t)o * NN * KT;

  const int tid = threadIdx.x;
  const int w = tid >> 6;
  const int l = tid & 63;
  const int wm = w >> 1, wn = w & 1;
  const int l8 = l & 7, ld8 = l >> 3;
  const int src_unit = l8 ^ (ld8 & 7);

  const u16* pA[MR];
  #pragma unroll
  for (int j = 0; j < MR; ++j) {
    int r = m_start + (j * 4 + w) * 8 + ld8;
    if (r >= g1) r = g1 - 1;
    pA[j] = A + (size_t)r * KT + src_unit * 8;
  }
  const u16* pB[4];
  #pragma unroll
  for (int j = 0; j < 4; ++j) {
    const int nr = n_start + (j * 4 + w) * 8 + ld8;
    pB[j] = Bo + (size_t)nr * KT + src_unit * 8;
  }

#define STAGE(dst_off)                                                         \
  {                                                                            \
    _Pragma("unroll")                                                          \
    for (int j = 0; j < MR; ++j)                                               \
      __builtin_amdgcn_global_load_lds((as1_cvp)pA[j],                         \
          (as3_vp)(smem + (dst_off) + (j * 4 + w) * 1024), 16, 0, 0);          \
    _Pragma("unroll")                                                          \
    for (int j = 0; j < 4; ++j)                                                \
      __builtin_amdgcn_global_load_lds((as1_cvp)pB[j],                         \
          (as3_vp)(smem + (dst_off) + ABUF + (j * 4 + w) * 1024), 16, 0, 0);   \
    _Pragma("unroll") for (int j = 0; j < MR; ++j) pA[j] += 64;                \
    _Pragma("unroll") for (int j = 0; j < 4; ++j) pB[j] += 64;                 \
  }

  const int lrow = l & 15;
  const int lx = l & 7;
  const int lu = l >> 4;
  int offA[MR][2], offB[4][2];
  #pragma unroll
  for (int a = 0; a < MR; ++a)
    #pragma unroll
    for (int kk = 0; kk < 2; ++kk)
      offA[a][kk] = (wm * (TM / 2) + a * 16 + lrow) * 128 + (((kk * 4 + lu) ^ lx) << 4);
  #pragma unroll
  for (int b = 0; b < 4; ++b)
    #pragma unroll
    for (int kk = 0; kk < 2; ++kk)
      offB[b][kk] = (wn * 64 + b * 16 + lrow) * 128 + (((kk * 4 + lu) ^ lx) << 4);

  f32x4 acc[MR][4] = {};

  const int nK = KT >> 6;
  STAGE(0);
  for (int kt = 0; kt < nK; ++kt) {
    const int cur = (kt & 1) * BSTR;
    if (kt + 1 < nK) {
      STAGE(BSTR - cur);
      asm volatile("s_waitcnt vmcnt(6)" ::: "memory");
    } else {
      asm volatile("s_waitcnt vmcnt(0)" ::: "memory");
    }
    __builtin_amdgcn_s_barrier();

    bf16x8 af[MR][2], bfr[4][2];
    #pragma unroll
    for (int a = 0; a < MR; ++a)
      #pragma unroll
      for (int kk = 0; kk < 2; ++kk)
        af[a][kk] = *(const bf16x8*)(smem + cur + offA[a][kk]);
    #pragma unroll
    for (int b = 0; b < 4; ++b)
      #pragma unroll
      for (int kk = 0; kk < 2; ++kk)
        bfr[b][kk] = *(const bf16x8*)(smem + cur + ABUF + offB[b][kk]);
    asm volatile("s_waitcnt lgkmcnt(0)" ::: "memory");
    __builtin_amdgcn_s_barrier();

    __builtin_amdgcn_s_setprio(1);
    #pragma unroll
    for (int kk = 0; kk < 2; ++kk)
      #pragma unroll
      for (int a = 0; a < MR; ++a)
        #pragma unroll
        for (int b = 0; b < 4; ++b)
          acc[a][b] = __builtin_amdgcn_mfma_f32_16x16x32_bf16(af[a][kk], bfr[b][kk], acc[a][b], 0, 0, 0);
    __builtin_amdgcn_s_setprio(0);
  }
#undef STAGE

  const int col_l = l & 15;
  const int row_l = (l >> 4) << 2;
  #pragma unroll
  for (int a = 0; a < MR; ++a) {
    #pragma unroll
    for (int b = 0; b < 4; ++b) {
      const int n = n_start + wn * 64 + b * 16 + col_l;
      const float bv = bias[n];
      #pragma unroll
      for (int r = 0; r < 4; ++r) {
        const int p = m_start + wm * (TM / 2) + a * 16 + row_l + r;
        if (p < g1) outF[(size_t)perm[p] * NN + n] = acc[a][b][r] + bv;
      }
    }
  }
}

// ---- k2: GEMM1 (blocks 0..319) ∥ W2T transpose (blocks 320..2367) ----
__global__ __launch_bounds__(256, 2) void gemm1_w2t_kernel(
    const u16* __restrict__ Xs, const u16* __restrict__ W1T,
    const float* __restrict__ b1, const int* __restrict__ starts,
    const int* __restrict__ tmap128, u16* __restrict__ Hs,
    const float* __restrict__ W2, u16* __restrict__ W2T) {
  __shared__ char smem[65536];
  const int bid = blockIdx.x;
  if (bid < 320) {
    gemm1_body(smem, bid, Xs, W1T, b1, starts, tmap128, Hs);
  } else {
    const int b = bid - 320;
    const int xcd = b & 7, i = b >> 3;
    const int tx = (xcd << 1) | (i & 1);
    const int ty = (i >> 1) & 31;
    const int o = i >> 6;
    wtrans_body((float(*)[65])smem, W2, W2T, 2048, 1024, tx, ty, o);
  }
}

// ---- k3: GEMM2 ----
__global__ __launch_bounds__(256, 2) void gemm2_kernel(
    const u16* __restrict__ Hs, const u16* __restrict__ W2T,
    const float* __restrict__ b2, const int* __restrict__ starts,
    const int* __restrict__ tmap64, const int* __restrict__ perm,
    float* __restrict__ out) {
  __shared__ char smem[49152];
  gemm2_body(smem, blockIdx.x, Hs, W2T, b2, starts, tmap64, perm, out);
}

extern "C" void kernel_launch(void* const* d_in, const int* in_sizes, int n_in,
                              void* d_out, int out_size, void* d_ws, size_t ws_size,
                              hipStream_t stream) {
  (void)n_in; (void)out_size; (void)ws_size;
  const float* x   = (const float*)d_in[0];
  const int*   idx = (const int*)d_in[1];
  const float* W1  = (const float*)d_in[2];
  const float* b1  = (const float*)d_in[3];
  const float* W2  = (const float*)d_in[4];
  const float* b2  = (const float*)d_in[5];
  float* out = (float*)d_out;

  const int B = in_sizes[1];  // 2048

  // workspace layout (~44.06 MB)
  char* ws = (char*)d_ws;
  u16* W1T     = (u16*)(ws);                    // 16 MB [o][N=2048][K=1024]
  u16* W2T     = (u16*)(ws + 16777216);         // 16 MB [o][N=1024][K=2048]
  u16* Xs      = (u16*)(ws + 33554432);         // B*1024 bf16 = 4 MB (sorted)
  u16* Hs      = (u16*)(ws + 37748736);         // B*2048 bf16 = 8 MB (sorted)
  int* perm    = (int*)(ws + 46137344);         // B ints
  int* starts  = (int*)(ws + 46137344 + 8192);  // 5 ints
  int* tmap128 = starts + 64;                   // 20 ints
  int* tmap64  = starts + 128;                  // 40 ints

  hist_perm_kernel<<<1, 256, 0, stream>>>(idx, B, starts, perm, tmap128, tmap64);
  w1t_gather_kernel<<<2048 + B, 256, 0, stream>>>(W1, W1T, x, perm, Xs);
  gemm1_w2t_kernel<<<320 + 2048, 256, 0, stream>>>(
      Xs, W1T, b1, starts, tmap128, Hs, W2, W2T);
  gemm2_kernel<<<320, 256, 0, stream>>>(Hs, W2T, b2, starts, tmap64, perm, out);
}